// Round 2
// baseline (95.064 us; speedup 1.0000x reference)
//
#include <hip/hip_runtime.h>

// FHE BSGS: out[b,s] = sum_{t=0..15} x[b,(s+2^t)&0xFFFF] * diag[t,s], rolled by 32768.
// Roll by S/2 on the 2^16 ring == store to column s ^ 0x8000 (coalesced).
//
// v8: v6 structure (diag-in-registers, barrier-free, 9 x-loads/row via wave shuffles)
// with the byte-bound levers pulled:
//   - NB 4 -> 8, grid 1024 -> 512: diag re-reads halve (67 -> 34 MB requests);
//     each XCD now owns exactly ONE batch-group (y = bid&7 = XCD), so the group's
//     x slice (8 rows = 2 MB, 9x reuse) is L2-resident with no cross-XCD duplication.
//   - diag loads + out stores are non-temporal: both are single-touch per XCD
//     (diag line read by exactly one block now), so keep them from evicting x.
// Evidence for byte-bound: bsgs never makes top-5 dispatches (runs <43us under
// profile, ~5.5+ TB/s request service ~= HBM stream rate; fills do 6.2 TB/s), and
// the v7 occupancy experiment was exactly neutral.

#define SLOTS 65536
#define MASK  65535
#define NB    8

typedef __attribute__((ext_vector_type(4))) float f4v;

__device__ __forceinline__ float4 ntload4(const float* p) {
    f4v v = __builtin_nontemporal_load((const f4v*)p);
    return make_float4(v.x, v.y, v.z, v.w);
}
__device__ __forceinline__ void ntstore4(float* p, const float4 v) {
    f4v t = {v.x, v.y, v.z, v.w};
    __builtin_nontemporal_store(t, (f4v*)p);
}

__device__ __forceinline__ float4 shfl4(const float4 v, int lsel) {
    return make_float4(__shfl(v.x, lsel, 64), __shfl(v.y, lsel, 64),
                       __shfl(v.z, lsel, 64), __shfl(v.w, lsel, 64));
}

__global__ __launch_bounds__(256) void bsgs_kernel(
    const float* __restrict__ x,
    const float* __restrict__ diag,
    float* __restrict__ out)
{
    const int bid  = blockIdx.x;          // 0..511
    const int y    = bid & 7;             // batch group == XCD (bid%8 round-robin)
    const int xidx = bid >> 3;            // column tile 0..63
    const int j    = xidx * 1024 + threadIdx.x * 4;   // column base (multiple of 4)
    const int bg   = y * NB;
    const int lane = threadIdx.x & 63;

    // diag[t, j..j+3], t=0..15 -- reused across NB batch rows, single-touch per XCD
    // (NT: don't let it evict the x slice from L2).
    float4 dreg[16];
#pragma unroll
    for (int t = 0; t < 16; ++t)
        dreg[t] = ntload4(diag + t * SLOTS + j);

    float4 acc[NB];
#pragma unroll
    for (int b = 0; b < NB; ++b) acc[b] = make_float4(0.f, 0.f, 0.f, 0.f);

#pragma unroll
    for (int b = 0; b < NB; ++b) {
        const float* __restrict__ xr = x + (size_t)(bg + b) * SLOTS;

        // 9 loads per row: vA, vE, and the 7 big shifts. (x has 9x reuse within
        // the XCD -> normal cached loads.)
        const float4 vA = *(const float4*)(xr + j);
        const float4 vE = *(const float4*)(xr + ((j + 256) & MASK));
        float4 vd[7];
#pragma unroll
        for (int t = 9; t < 16; ++t)
            vd[t - 9] = *(const float4*)(xr + ((j + (1 << t)) & MASK));

        // Windows at shifts 4,8,16,32,64,128 via cross-lane shuffles (DS pipe).
        float4 w[6];
#pragma unroll
        for (int i = 0; i < 6; ++i) {
            const int k  = 1 << i;             // lane offset = shift/4
            const int lp = lane + k;           // source lane (may spill into vE's window)
            const int ls = lp & 63;
            const float4 a = shfl4(vA, ls);
            const float4 e = shfl4(vE, ls);
            const bool useA = lp < 64;
            w[i] = make_float4(useA ? a.x : e.x, useA ? a.y : e.y,
                               useA ? a.z : e.z, useA ? a.w : e.w);
        }

        // t=0 (shift 1): (vA.y, vA.z, vA.w, w0.x);  t=1 (shift 2): (vA.z, vA.w, w0.x, w0.y)
        acc[b].x += vA.y   * dreg[0].x + vA.z   * dreg[1].x;
        acc[b].y += vA.z   * dreg[0].y + vA.w   * dreg[1].y;
        acc[b].z += vA.w   * dreg[0].z + w[0].x * dreg[1].z;
        acc[b].w += w[0].x * dreg[0].w + w[0].y * dreg[1].w;

        // t=2..7 (shifts 4..128): shuffle windows
#pragma unroll
        for (int t = 2; t <= 7; ++t) {
            const float4 v = w[t - 2];
            acc[b].x += v.x * dreg[t].x; acc[b].y += v.y * dreg[t].y;
            acc[b].z += v.z * dreg[t].z; acc[b].w += v.w * dreg[t].w;
        }
        // t=8 (shift 256): vE directly
        acc[b].x += vE.x * dreg[8].x; acc[b].y += vE.y * dreg[8].y;
        acc[b].z += vE.z * dreg[8].z; acc[b].w += vE.w * dreg[8].w;
        // t=9..15 (shifts 512..32768): direct loads
#pragma unroll
        for (int t = 9; t < 16; ++t) {
            const float4 v = vd[t - 9];
            acc[b].x += v.x * dreg[t].x; acc[b].y += v.y * dreg[t].y;
            acc[b].z += v.z * dreg[t].z; acc[b].w += v.w * dreg[t].w;
        }
    }

    // roll by 32768 == XOR top column bit; stores stay coalesced.
    // NT: out is write-once, keep it out of L2.
#pragma unroll
    for (int b = 0; b < NB; ++b)
        ntstore4(out + (size_t)(bg + b) * SLOTS + (j ^ 32768), acc[b]);
}

extern "C" void kernel_launch(void* const* d_in, const int* in_sizes, int n_in,
                              void* d_out, int out_size, void* d_ws, size_t ws_size,
                              hipStream_t stream) {
    const float* x    = (const float*)d_in[0];   // (64, 65536) fp32
    const float* diag = (const float*)d_in[1];   // (16, 65536) fp32
    float* out        = (float*)d_out;           // (64, 65536) fp32
    // d_in[2] = stride (1), d_in[3] = reps (1) -- compile-time constants here.

    bsgs_kernel<<<dim3(512), dim3(256), 0, stream>>>(x, diag, out);
}

// Round 3
// 91.839 us; speedup vs baseline: 1.0351x; 1.0351x over previous
//
#include <hip/hip_runtime.h>

// FHE BSGS: out[b,s] = sum_{t=0..15} x[b,(s+2^t)&0xFFFF] * diag[t,s], rolled by 32768.
// Roll by S/2 on the 2^16 ring == store to column s ^ 0x8000 (coalesced).
//
// v9: byte-reduction of v8 with the confounds removed.
// Working model (fits v6/v7/fills): time ~= total request bytes / ~6 TB/s per-CU
// VMEM service cap (~10 B/cyc/CU); occupancy above ~8 waves/CU is neutral (v7),
// so the lever is REQUEST BYTES. v8 cut bytes but regressed -- suspects are its
// NT hints (L2 bypass -> diag refetch from HBM) and register spills at NB=8
// (dreg 64 + acc 32 + temps ~60 = ~170 VGPR -> scratch traffic = extra requests).
// v9 keeps the byte win, drops the confounds:
//   - NB=8, 512 blocks (2/CU, all CUs busy): diag requests 67 -> 34 MB,
//     total 237 -> 202 MB.
//   - NO non-temporal hints anywhere.
//   - diag lives in LDS (64 KB/block, = 160KB/2 per CU), NOT registers: each
//     thread reads only its own sdiag[t][tid] (contiguous 1KB/wave ds_read_b128,
//     conflict-free). LDS = cheap spill arena; peak VGPR ~115-130, no scratch.
//   - y = bid&7 == XCD: each XCD exclusively owns 8 batch rows (2 MB x slice).

#define SLOTS 65536
#define MASK  65535
#define NB    8

__device__ __forceinline__ float4 shfl4(const float4 v, int lsel) {
    return make_float4(__shfl(v.x, lsel, 64), __shfl(v.y, lsel, 64),
                       __shfl(v.z, lsel, 64), __shfl(v.w, lsel, 64));
}

__global__ __launch_bounds__(256) void bsgs_kernel(
    const float* __restrict__ x,
    const float* __restrict__ diag,
    float* __restrict__ out)
{
    __shared__ float4 sdiag[16][256];     // 64 KB: diag[t, j..j+3] per thread

    const int bid  = blockIdx.x;          // 0..511
    const int y    = bid & 7;             // batch group == XCD (bid%8 round-robin)
    const int xidx = bid >> 3;            // column tile 0..63
    const int tid  = threadIdx.x;
    const int j    = xidx * 1024 + tid * 4;   // column base (multiple of 4)
    const int bg   = y * NB;
    const int lane = tid & 63;

    // Stage diag tile into LDS (register-pressure relief; 16 coalesced float4 loads).
#pragma unroll
    for (int t = 0; t < 16; ++t)
        sdiag[t][tid] = *(const float4*)(diag + t * SLOTS + j);
    __syncthreads();

    float4 acc[NB];
#pragma unroll
    for (int b = 0; b < NB; ++b) acc[b] = make_float4(0.f, 0.f, 0.f, 0.f);

#pragma unroll
    for (int b = 0; b < NB; ++b) {
        const float* __restrict__ xr = x + (size_t)(bg + b) * SLOTS;

        // 9 loads per row: vA, vE, and the 7 big shifts.
        const float4 vA = *(const float4*)(xr + j);
        const float4 vE = *(const float4*)(xr + ((j + 256) & MASK));
        float4 vd[7];
#pragma unroll
        for (int t = 9; t < 16; ++t)
            vd[t - 9] = *(const float4*)(xr + ((j + (1 << t)) & MASK));

        // Windows at shifts 4,8,16,32,64,128 via cross-lane shuffles (DS pipe).
        float4 w[6];
#pragma unroll
        for (int i = 0; i < 6; ++i) {
            const int k  = 1 << i;             // lane offset = shift/4
            const int lp = lane + k;           // source lane (may spill into vE's window)
            const int ls = lp & 63;
            const float4 a = shfl4(vA, ls);
            const float4 e = shfl4(vE, ls);
            const bool useA = lp < 64;
            w[i] = make_float4(useA ? a.x : e.x, useA ? a.y : e.y,
                               useA ? a.z : e.z, useA ? a.w : e.w);
        }

        // t=0 (shift 1): (vA.y, vA.z, vA.w, w0.x);  t=1 (shift 2): (vA.z, vA.w, w0.x, w0.y)
        {
            const float4 d0 = sdiag[0][tid];
            const float4 d1 = sdiag[1][tid];
            acc[b].x += vA.y   * d0.x + vA.z   * d1.x;
            acc[b].y += vA.z   * d0.y + vA.w   * d1.y;
            acc[b].z += vA.w   * d0.z + w[0].x * d1.z;
            acc[b].w += w[0].x * d0.w + w[0].y * d1.w;
        }

        // t=2..7 (shifts 4..128): shuffle windows
#pragma unroll
        for (int t = 2; t <= 7; ++t) {
            const float4 v = w[t - 2];
            const float4 d = sdiag[t][tid];
            acc[b].x += v.x * d.x; acc[b].y += v.y * d.y;
            acc[b].z += v.z * d.z; acc[b].w += v.w * d.w;
        }
        // t=8 (shift 256): vE directly
        {
            const float4 d = sdiag[8][tid];
            acc[b].x += vE.x * d.x; acc[b].y += vE.y * d.y;
            acc[b].z += vE.z * d.z; acc[b].w += vE.w * d.w;
        }
        // t=9..15 (shifts 512..32768): direct loads
#pragma unroll
        for (int t = 9; t < 16; ++t) {
            const float4 v = vd[t - 9];
            const float4 d = sdiag[t][tid];
            acc[b].x += v.x * d.x; acc[b].y += v.y * d.y;
            acc[b].z += v.z * d.z; acc[b].w += v.w * d.w;
        }
    }

    // roll by 32768 == XOR top column bit; stores stay coalesced
#pragma unroll
    for (int b = 0; b < NB; ++b)
        *(float4*)(out + (size_t)(bg + b) * SLOTS + (j ^ 32768)) = acc[b];
}

extern "C" void kernel_launch(void* const* d_in, const int* in_sizes, int n_in,
                              void* d_out, int out_size, void* d_ws, size_t ws_size,
                              hipStream_t stream) {
    const float* x    = (const float*)d_in[0];   // (64, 65536) fp32
    const float* diag = (const float*)d_in[1];   // (16, 65536) fp32
    float* out        = (float*)d_out;           // (64, 65536) fp32
    // d_in[2] = stride (1), d_in[3] = reps (1) -- compile-time constants here.

    bsgs_kernel<<<dim3(512), dim3(256), 0, stream>>>(x, diag, out);
}

// Round 4
// 82.862 us; speedup vs baseline: 1.1473x; 1.1083x over previous
//
#include <hip/hip_runtime.h>

// FHE BSGS: out[b,s] = sum_{t=0..15} x[b,(s+2^t)&0xFFFF] * diag[t,s], rolled by 32768.
// Roll by S/2 on the 2^16 ring == store to column s ^ 0x8000 (coalesced).
//
// v10: v6's proven shape (1024 blocks, NB=4, y=bid&15 -> group pinned to XCD,
// diag in registers) with an LDS strip replacing both the shuffle machinery and
// the mid-shift global loads.
// Evidence trail: v7 (2x waves, same blocks/bytes) neutral; v8/v9 (-15% bytes at
// 512 blocks) both regressed -> served rate depends on block count; v6's 237 MB
// at 1024 blocks ~= flat ~6 TB/s service. Lever: fewer request bytes at EXACTLY
// the v6 operating point.
//   - Stage x[row][J .. J+2048) (ring-wrapped) in LDS: 4 rows x 8 KB = 32 KB,
//     ONE barrier. Shifts 1..1024 (t=0..10) all become aligned conflict-free
//     ds_read_b128 at tid*4 + 2^t (strip lookahead 1024 covers them).
//   - Global x loads drop 9 -> 7 f4/row (strip 2 + big shifts t=11..15);
//     requests 237 -> 201 MB. All 48 bpermute-shuffles + cndmasks per row die.

#define SLOTS 65536
#define MASK  65535
#define NB    4
#define STRIPW 2048

__global__ __launch_bounds__(256) void bsgs_kernel(
    const float* __restrict__ x,
    const float* __restrict__ diag,
    float* __restrict__ out)
{
    __shared__ float sstrip[NB][STRIPW];   // 32 KB

    const int bid  = blockIdx.x;          // 0..1023
    const int y    = bid & 15;            // batch group (group -> XCD y%8, as v6)
    const int xidx = bid >> 4;            // column tile 0..63
    const int tid  = threadIdx.x;
    const int J    = xidx * 1024;
    const int j    = J + tid * 4;         // column base (multiple of 4)
    const int bg   = y * NB;

    // diag[t, j..j+3], t=0..15 -- reused across NB batch rows (64 VGPR, v6-proven).
    float4 dreg[16];
#pragma unroll
    for (int t = 0; t < 16; ++t)
        dreg[t] = *(const float4*)(diag + t * SLOTS + j);

    // Stage all NB strips: x[row][(J+i)&MASK], i in [0,2048). 2 f4 per row per thread.
#pragma unroll
    for (int b = 0; b < NB; ++b) {
        const float* __restrict__ xr = x + (size_t)(bg + b) * SLOTS;
#pragma unroll
        for (int h = 0; h < 2; ++h) {
            const int i = tid * 4 + h * 1024;
            *(float4*)(&sstrip[b][i]) = *(const float4*)(xr + ((J + i) & MASK));
        }
    }
    __syncthreads();   // the only barrier

    float4 acc[NB];
#pragma unroll
    for (int b = 0; b < NB; ++b) acc[b] = make_float4(0.f, 0.f, 0.f, 0.f);

#pragma unroll
    for (int b = 0; b < NB; ++b) {
        const float* __restrict__ xr = x + (size_t)(bg + b) * SLOTS;

        // Big shifts t=11..15 (2048..32768): direct global loads, issued first.
        float4 vd[5];
#pragma unroll
        for (int t = 11; t < 16; ++t)
            vd[t - 11] = *(const float4*)(xr + ((j + (1 << t)) & MASK));

        // All windows for shifts <=1024 from the LDS strip (aligned b128 reads).
        const float* sp = &sstrip[b][tid * 4];
        const float4 v0 = *(const float4*)(sp);        // shift 0 (for t=0,1 slides)
        const float4 w4 = *(const float4*)(sp + 4);    // shift 4 (t=2; t=0,1 tail)

        // t=0 (shift 1): (v0.y, v0.z, v0.w, w4.x); t=1 (shift 2): (v0.z, v0.w, w4.x, w4.y)
        acc[b].x += v0.y * dreg[0].x + v0.z * dreg[1].x;
        acc[b].y += v0.z * dreg[0].y + v0.w * dreg[1].y;
        acc[b].z += v0.w * dreg[0].z + w4.x * dreg[1].z;
        acc[b].w += w4.x * dreg[0].w + w4.y * dreg[1].w;

        // t=2 (shift 4): w4 itself
        acc[b].x += w4.x * dreg[2].x; acc[b].y += w4.y * dreg[2].y;
        acc[b].z += w4.z * dreg[2].z; acc[b].w += w4.w * dreg[2].w;

        // t=3..10 (shifts 8..1024): strip reads at tid*4 + 2^t
#pragma unroll
        for (int t = 3; t <= 10; ++t) {
            const float4 v = *(const float4*)(sp + (1 << t));
            acc[b].x += v.x * dreg[t].x; acc[b].y += v.y * dreg[t].y;
            acc[b].z += v.z * dreg[t].z; acc[b].w += v.w * dreg[t].w;
        }

        // t=11..15: the staged global loads
#pragma unroll
        for (int t = 11; t < 16; ++t) {
            const float4 v = vd[t - 11];
            acc[b].x += v.x * dreg[t].x; acc[b].y += v.y * dreg[t].y;
            acc[b].z += v.z * dreg[t].z; acc[b].w += v.w * dreg[t].w;
        }
    }

    // roll by 32768 == XOR top column bit; stores stay coalesced
#pragma unroll
    for (int b = 0; b < NB; ++b)
        *(float4*)(out + (size_t)(bg + b) * SLOTS + (j ^ 32768)) = acc[b];
}

extern "C" void kernel_launch(void* const* d_in, const int* in_sizes, int n_in,
                              void* d_out, int out_size, void* d_ws, size_t ws_size,
                              hipStream_t stream) {
    const float* x    = (const float*)d_in[0];   // (64, 65536) fp32
    const float* diag = (const float*)d_in[1];   // (16, 65536) fp32
    float* out        = (float*)d_out;           // (64, 65536) fp32
    // d_in[2] = stride (1), d_in[3] = reps (1) -- compile-time constants here.

    bsgs_kernel<<<dim3(1024), dim3(256), 0, stream>>>(x, diag, out);
}